// Round 11
// baseline (279.670 us; speedup 1.0000x reference)
//
#include <hip/hip_runtime.h>
#include <hip/hip_bf16.h>

#define N_NODES   50000
#define N_USERS   20000
#define N_EDGES   800000
#define DIM       256
#define NHEAD     8
#define DKH       32
#define NBLK_SCAN ((N_NODES + 255) / 256)   // 196
#define NGRP      (N_NODES / 16)            // 3125
#define NGRP_PAD  3128
#define SLOTS_NODE (NGRP * 8 * 64)          // 1.6M fragment slots per node matrix
#define NBLK_CAST (SLOTS_NODE / 256)        // 6250
#define NBLK_HIST ((N_EDGES + 255) / 256)   // 3125
#define NBLK_G64  (NGRP_PAD / 4)            // 782 row-tiles of 64
#define KVROW     768                       // 256B K-fp8 + 512B V-bf16

typedef __attribute__((ext_vector_type(8))) short bf16x8;
typedef __attribute__((ext_vector_type(4))) float f32x4;
typedef __attribute__((ext_vector_type(4))) unsigned short u16x4;
typedef __attribute__((ext_vector_type(8))) unsigned short u16x8;

__device__ inline unsigned short f2bf(float f) {
    union { __hip_bfloat16 b; unsigned short u; } cv;
    cv.b = __float2bfloat16(f);
    return cv.u;
}
__device__ inline float bf2f(unsigned short u) {
    return __uint_as_float(((unsigned int)u) << 16);
}
__device__ inline unsigned char f2fp8(float f) {
    unsigned int p = __builtin_amdgcn_cvt_pk_fp8_f32(f, f, 0, false);
    return (unsigned char)(p & 0xff);
}

// Fragment-tiled layout: elem (r, d) -> ((r>>4)*8 + (d>>5))*512 + ((d>>3)&3)*128 + (r&15)*8 + (d&7)
// One MFMA fragment = 64 lanes x 8 bf16 contiguous = 1KB coalesced.

// ---------------- prep: weight cast | input cast | degree histogram (split by blockIdx) ----------------
__global__ void prep_kernel(const float* __restrict__ Wq, const float* __restrict__ Wk,
                            const float* __restrict__ Wv, const float* __restrict__ Wo,
                            unsigned short* __restrict__ Wb2,
                            const float* __restrict__ x,
                            const float* __restrict__ user, const float* __restrict__ item,
                            unsigned short* __restrict__ xb2, unsigned short* __restrict__ tb2,
                            const int* __restrict__ col, int* __restrict__ cnt)
{
    int b = blockIdx.x;
    if (b < 128) {
        int gid = b * 256 + threadIdx.x;
        const float* srcs[4] = { Wq, Wk, Wv, Wo };
        int m = gid >> 13, slot = gid & 8191;
        int lane = slot & 63, ks = (slot >> 6) & 7, g = slot >> 9;
        int c = g * 16 + (lane & 15);
        int d = ks * 32 + (lane >> 4) * 8;
        const float* s = srcs[m] + (size_t)c * DIM + d;
        float4 f0 = *(const float4*)s, f1 = *(const float4*)(s + 4);
        u16x8 o = { f2bf(f0.x), f2bf(f0.y), f2bf(f0.z), f2bf(f0.w),
                    f2bf(f1.x), f2bf(f1.y), f2bf(f1.z), f2bf(f1.w) };
        *(u16x8*)(Wb2 + (size_t)m * 65536 + (size_t)slot * 8) = o;
    } else if (b < 128 + NBLK_CAST) {
        int slot = (b - 128) * 256 + threadIdx.x;
        int lane = slot & 63, ks = (slot >> 6) & 7, g = slot >> 9;
        int r = g * 16 + (lane & 15);
        int d = ks * 32 + (lane >> 4) * 8;

        const float* sx = x + (size_t)r * DIM + d;
        float4 f0 = *(const float4*)sx, f1 = *(const float4*)(sx + 4);
        u16x8 xo = { f2bf(f0.x), f2bf(f0.y), f2bf(f0.z), f2bf(f0.w),
                     f2bf(f1.x), f2bf(f1.y), f2bf(f1.z), f2bf(f1.w) };
        *(u16x8*)(xb2 + (size_t)slot * 8) = xo;

        const float* st = (r < N_USERS) ? user + (size_t)r * DIM + d
                                        : item + (size_t)(r - N_USERS) * DIM + d;
        float4 t0 = *(const float4*)st, t1 = *(const float4*)(st + 4);
        u16x8 to = { f2bf(t0.x), f2bf(t0.y), f2bf(t0.z), f2bf(t0.w),
                     f2bf(t1.x), f2bf(t1.y), f2bf(t1.z), f2bf(t1.w) };
        *(u16x8*)(tb2 + (size_t)slot * 8) = to;
    } else {
        int e = (b - 128 - NBLK_CAST) * 256 + threadIdx.x;
        if (e < N_EDGES) atomicAdd(&cnt[col[e]], 1);
    }
}

// ---------------- 64-row x 256-col register-direct MFMA GEMM core ----------------
// Each block reads its A panel exactly once (full output width per block).
__device__ __forceinline__ void mfma_core64(const unsigned short* __restrict__ A2,
                                            const unsigned short* __restrict__ W2,
                                            int row0, f32x4 acc[2][8],
                                            int lane, int wid)
{
    const int gA = (row0 >> 4) + (wid >> 1) * 2;   // wm = wid>>1: rows wm*32
    const int gB = (wid & 1) * 8;                  // wn = wid&1: cols wn*128
    #pragma unroll
    for (int ks = 0; ks < 8; ++ks) {
        bf16x8 a[2], b[8];
        #pragma unroll
        for (int i = 0; i < 2; ++i)
            a[i] = *(const bf16x8*)(A2 + (size_t)((gA + i) * 8 + ks) * 512 + lane * 8);
        #pragma unroll
        for (int j = 0; j < 8; ++j)
            b[j] = *(const bf16x8*)(W2 + (size_t)((gB + j) * 8 + ks) * 512 + lane * 8);
        #pragma unroll
        for (int i = 0; i < 2; ++i)
            #pragma unroll
            for (int j = 0; j < 8; ++j)
                acc[i][j] = __builtin_amdgcn_mfma_f32_16x16x32_bf16(a[i], b[j], acc[i][j], 0, 0, 0);
    }
}

// Epilogue MODE: 0 = fp32 linear, 1 = bf16 linear, 2 = KV K-half (fp8), 3 = KV V-half (bf16)
template<int MODE>
__device__ __forceinline__ void epilogue64(f32x4 acc[2][8], const float* bias, void* Cv,
                                           int row0, int M, int lane, int wid)
{
    const int wm = wid >> 1, wn = wid & 1;
    const int lr = lane & 15, lk = lane >> 4;
    float* Cf = (float*)Cv;
    unsigned short* Cb = (unsigned short*)Cv;
    unsigned char* C8 = (unsigned char*)Cv;
    #pragma unroll
    for (int i = 0; i < 2; ++i) {
        #pragma unroll
        for (int r = 0; r < 4; ++r) {
            int grow = row0 + wm * 32 + i * 16 + lk * 4 + r;
            if (grow >= M) continue;
            #pragma unroll
            for (int j = 0; j < 8; ++j) {
                int gcol = wn * 128 + j * 16 + lr;
                float val = acc[i][j][r] + bias[gcol];
                if constexpr (MODE == 0) {
                    Cf[(size_t)grow * 256 + gcol] = val;
                } else if constexpr (MODE == 1) {
                    Cb[(size_t)grow * 256 + gcol] = f2bf(val);
                } else if constexpr (MODE == 2) {
                    C8[(size_t)grow * KVROW + gcol] = f2fp8(val);
                } else {
                    *(unsigned short*)(C8 + (size_t)grow * KVROW + 256 + gcol * 2) = f2bf(val);
                }
            }
        }
    }
}

// Fused Q/K/V GEMM: grid (NBLK_G64, 3), mat = blockIdx.y (0:Q,1:K,2:V)
__global__ __launch_bounds__(256) void gemm_qkv_reg(
    const unsigned short* __restrict__ tb2, const unsigned short* __restrict__ xb2,
    const unsigned short* __restrict__ Wb2,
    const float* __restrict__ bq, const float* __restrict__ bk, const float* __restrict__ bv,
    unsigned short* __restrict__ Qb, unsigned char* __restrict__ KVb, int M)
{
    const int tid = threadIdx.x;
    const int lane = tid & 63, wid = tid >> 6;
    const int row0 = blockIdx.x * 64;
    const int mat  = blockIdx.y;

    const unsigned short* A2 = (mat == 2) ? xb2 : tb2;
    const unsigned short* W2 = Wb2 + (size_t)mat * 65536;

    f32x4 acc[2][8];
    #pragma unroll
    for (int i = 0; i < 2; ++i)
        #pragma unroll
        for (int j = 0; j < 8; ++j) acc[i][j] = (f32x4){0.f, 0.f, 0.f, 0.f};

    mfma_core64(A2, W2, row0, acc, lane, wid);

    if (mat == 0)      epilogue64<1>(acc, bq, Qb,  row0, M, lane, wid);
    else if (mat == 1) epilogue64<2>(acc, bk, KVb, row0, M, lane, wid);
    else               epilogue64<3>(acc, bv, KVb, row0, M, lane, wid);
}

// Final O GEMM: grid (NBLK_G64, 1), fp32 out
__global__ __launch_bounds__(256) void gemm_o_reg(
    const unsigned short* __restrict__ A2,
    const unsigned short* __restrict__ Wb2, const float* __restrict__ bo,
    float* __restrict__ C, int M)
{
    const int tid = threadIdx.x;
    const int lane = tid & 63, wid = tid >> 6;
    const int row0 = blockIdx.x * 64;

    f32x4 acc[2][8];
    #pragma unroll
    for (int i = 0; i < 2; ++i)
        #pragma unroll
        for (int j = 0; j < 8; ++j) acc[i][j] = (f32x4){0.f, 0.f, 0.f, 0.f};

    mfma_core64(A2, Wb2 + 3 * 65536, row0, acc, lane, wid);
    epilogue64<0>(acc, bo, C, row0, M, lane, wid);
}

// ---------------- CSR build ----------------
__global__ __launch_bounds__(256) void scan_blk_kernel(const int* __restrict__ cnt,
                                                       int* __restrict__ offs_tmp,
                                                       int* __restrict__ bsum) {
    __shared__ int s[256];
    int b = blockIdx.x, t = threadIdx.x;
    int i = b * 256 + t;
    int v = (i < N_NODES) ? cnt[i] : 0;
    s[t] = v;
    __syncthreads();
    #pragma unroll
    for (int d = 1; d < 256; d <<= 1) {
        int u = (t >= d) ? s[t - d] : 0;
        __syncthreads();
        s[t] += u;
        __syncthreads();
    }
    if (i < N_NODES) offs_tmp[i] = s[t] - v;
    if (t == 255) bsum[b] = s[255];
}

__global__ __launch_bounds__(256) void scan_top_kernel(int* __restrict__ bsum) {
    __shared__ int s[256];
    int t = threadIdx.x;
    int v = (t < NBLK_SCAN) ? bsum[t] : 0;
    s[t] = v;
    __syncthreads();
    #pragma unroll
    for (int d = 1; d < 256; d <<= 1) {
        int u = (t >= d) ? s[t - d] : 0;
        __syncthreads();
        s[t] += u;
        __syncthreads();
    }
    if (t < NBLK_SCAN) bsum[t] = s[t] - v;
}

__global__ __launch_bounds__(256) void scan_add_kernel(const int* __restrict__ offs_tmp,
                                                       const int* __restrict__ bsum,
                                                       int* __restrict__ offs,
                                                       int* __restrict__ cursor) {
    int i = blockIdx.x * 256 + threadIdx.x;
    if (i == 0) offs[N_NODES] = N_EDGES;
    if (i >= N_NODES) return;
    int o = offs_tmp[i] + bsum[blockIdx.x];
    offs[i] = o;
    cursor[i] = o;
}

__global__ void scatter_kernel(const int* __restrict__ row, const int* __restrict__ col,
                               int* __restrict__ cursor, int* __restrict__ esrc) {
    int e = blockIdx.x * blockDim.x + threadIdx.x;
    if (e >= N_EDGES) return;
    int c = col[e];
    int p = atomicAdd(&cursor[c], 1);
    esrc[p] = row[e];
}

// ---------------- fused edge phase: one wave per destination node ----------------
// K fp8 (4B/lane) + V bf16 (8B/lane): 768B/edge row. 8-deep gather pipeline.
__global__ __launch_bounds__(256) void node_fused_kernel(
    const unsigned short* __restrict__ Qb, const unsigned char* __restrict__ KVb,
    const float* __restrict__ rel,
    const int* __restrict__ offs, const int* __restrict__ esrc,
    unsigned short* __restrict__ outagg2)
{
    const float SC = 0.17677669529663687f;  // 1/sqrt(32)
    int wid = (blockIdx.x * blockDim.x + threadIdx.x) >> 6;
    int lane = threadIdx.x & 63;
    if (wid >= N_NODES) return;
    int beg = offs[wid], end = offs[wid + 1];
    int d0 = lane * 4;
    const unsigned char* kbase = KVb + lane * 4;
    const unsigned char* vbase = KVb + 256 + lane * 8;

    u16x4 qb4 = *(const u16x4*)(Qb + (size_t)wid * DIM + d0);
    float qx = bf2f(qb4[0]), qy = bf2f(qb4[1]), qz = bf2f(qb4[2]), qw = bf2f(qb4[3]);
    float4 rl = *(const float4*)(rel + d0);

    float p0 = qx * rl.x + qy * rl.y + qz * rl.z + qw * rl.w;
    p0 += __shfl_xor(p0, 1);
    p0 += __shfl_xor(p0, 2);
    p0 += __shfl_xor(p0, 4);

    float den = 0.f;
    float4 acc = make_float4(0.f, 0.f, 0.f, 0.f);

    for (int base = beg; base < end; base += 64) {
        int n = end - base; if (n > 64) n = 64;
        int idx = base + lane; if (idx >= end) idx = end - 1;
        int my = esrc[idx];
        int j = 0;
        for (; j + 8 <= n; j += 8) {
            unsigned int kw[8]; u16x4 vv[8];
            #pragma unroll
            for (int u = 0; u < 8; ++u) {
                int r = __shfl(my, j + u);
                size_t ro = (size_t)r * KVROW;
                kw[u] = *(const unsigned int*)(kbase + ro);
                vv[u] = *(const u16x4*)(vbase + ro);
            }
            float s[8];
            #pragma unroll
            for (int u = 0; u < 8; ++u)
                s[u] = qx * __builtin_amdgcn_cvt_f32_fp8(kw[u], 0)
                     + qy * __builtin_amdgcn_cvt_f32_fp8(kw[u], 1)
                     + qz * __builtin_amdgcn_cvt_f32_fp8(kw[u], 2)
                     + qw * __builtin_amdgcn_cvt_f32_fp8(kw[u], 3);
            #pragma unroll
            for (int u = 0; u < 8; ++u) {
                s[u] += __shfl_xor(s[u], 1);
                s[u] += __shfl_xor(s[u], 2);
                s[u] += __shfl_xor(s[u], 4);
            }
            #pragma unroll
            for (int u = 0; u < 8; ++u) {
                float w = __expf((s[u] + p0) * SC);
                den += w;
                acc.x += w * bf2f(vv[u][0]); acc.y += w * bf2f(vv[u][1]);
                acc.z += w * bf2f(vv[u][2]); acc.w += w * bf2f(vv[u][3]);
            }
        }
        for (; j + 4 <= n; j += 4) {
            unsigned int kw[4]; u16x4 vv[4];
            #pragma unroll
            for (int u = 0; u < 4; ++u) {
                int r = __shfl(my, j + u);
                size_t ro = (size_t)r * KVROW;
                kw[u] = *(const unsigned int*)(kbase + ro);
                vv[u] = *(const u16x4*)(vbase + ro);
            }
            float s[4];
            #pragma unroll
            for (int u = 0; u < 4; ++u)
                s[u] = qx * __builtin_amdgcn_cvt_f32_fp8(kw[u], 0)
                     + qy * __builtin_amdgcn_cvt_f32_fp8(kw[u], 1)
                     + qz * __builtin_amdgcn_cvt_f32_fp8(kw[u], 2)
                     + qw * __builtin_amdgcn_cvt_f32_fp8(kw[u], 3);
            #pragma unroll
            for (int u = 0; u < 4; ++u) {
                s[u] += __shfl_xor(s[u], 1);
                s[u] += __shfl_xor(s[u], 2);
                s[u] += __shfl_xor(s[u], 4);
            }
            #pragma unroll
            for (int u = 0; u < 4; ++u) {
                float w = __expf((s[u] + p0) * SC);
                den += w;
                acc.x += w * bf2f(vv[u][0]); acc.y += w * bf2f(vv[u][1]);
                acc.z += w * bf2f(vv[u][2]); acc.w += w * bf2f(vv[u][3]);
            }
        }
        for (; j < n; ++j) {
            int r = __shfl(my, j);
            size_t ro = (size_t)r * KVROW;
            unsigned int kw = *(const unsigned int*)(kbase + ro);
            u16x4 vv = *(const u16x4*)(vbase + ro);
            float s0 = qx * __builtin_amdgcn_cvt_f32_fp8(kw, 0)
                     + qy * __builtin_amdgcn_cvt_f32_fp8(kw, 1)
                     + qz * __builtin_amdgcn_cvt_f32_fp8(kw, 2)
                     + qw * __builtin_amdgcn_cvt_f32_fp8(kw, 3);
            s0 += __shfl_xor(s0, 1);
            s0 += __shfl_xor(s0, 2);
            s0 += __shfl_xor(s0, 4);
            float w0 = __expf((s0 + p0) * SC);
            den += w0;
            acc.x += w0 * bf2f(vv[0]); acc.y += w0 * bf2f(vv[1]);
            acc.z += w0 * bf2f(vv[2]); acc.w += w0 * bf2f(vv[3]);
        }
    }
    float rden = (end > beg) ? 1.f / den : 0.f;
    u16x4 o = { f2bf(acc.x * rden), f2bf(acc.y * rden),
                f2bf(acc.z * rden), f2bf(acc.w * rden) };
    int ks = lane >> 3, lk = (lane >> 1) & 3, e4 = (lane & 1) * 4;
    size_t toff = ((size_t)(wid >> 4) * 8 + ks) * 512 + (lk * 16 + (wid & 15)) * 8 + e4;
    *(u16x4*)(outagg2 + toff) = o;
}

extern "C" void kernel_launch(void* const* d_in, const int* in_sizes, int n_in,
                              void* d_out, int out_size, void* d_ws, size_t ws_size,
                              hipStream_t stream) {
    const float* x    = (const float*)d_in[0];
    const int*   row  = (const int*)d_in[1];
    const int*   col  = (const int*)d_in[2];
    const float* rel  = (const float*)d_in[3];
    const float* user = (const float*)d_in[4];
    const float* item = (const float*)d_in[5];
    const float* Wq   = (const float*)d_in[6];
    const float* bq   = (const float*)d_in[7];
    const float* Wk   = (const float*)d_in[8];
    const float* bk   = (const float*)d_in[9];
    const float* Wv   = (const float*)d_in[10];
    const float* bv   = (const float*)d_in[11];
    const float* Wo   = (const float*)d_in[12];
    const float* bo   = (const float*)d_in[13];

    char* ws = (char*)d_ws;
    size_t off = 0;
    auto alloc = [&](size_t bytes) -> void* {
        void* p = ws + off;
        off = (off + bytes + 255) & ~(size_t)255;
        return p;
    };
    const size_t tiled_sz = (size_t)NGRP_PAD * 4096 * 2;
    unsigned short* Qb      = (unsigned short*)alloc((size_t)N_NODES * DIM * 2);
    unsigned char*  KVb     = (unsigned char*)alloc((size_t)N_NODES * KVROW);
    unsigned short* xb2     = (unsigned short*)alloc(tiled_sz);
    unsigned short* tb2     = (unsigned short*)alloc(tiled_sz);
    unsigned short* outagg2 = (unsigned short*)alloc(tiled_sz);
    unsigned short* Wb2     = (unsigned short*)alloc((size_t)4 * 65536 * 2);
    int*   cnt      = (int*)alloc((size_t)N_NODES * 4);
    int*   offs     = (int*)alloc((size_t)(N_NODES + 1) * 4);
    int*   offs_tmp = (int*)alloc((size_t)N_NODES * 4);
    int*   bsum     = (int*)alloc((size_t)NBLK_SCAN * 4);
    int*   esrc     = (int*)alloc((size_t)N_EDGES * 4);

    hipMemsetAsync(cnt, 0, (size_t)N_NODES * 4, stream);

    prep_kernel<<<128 + NBLK_CAST + NBLK_HIST, 256, 0, stream>>>(
        Wq, Wk, Wv, Wo, Wb2, x, user, item, xb2, tb2, col, cnt);
    scan_blk_kernel<<<NBLK_SCAN, 256, 0, stream>>>(cnt, offs_tmp, bsum);
    scan_top_kernel<<<1, 256, 0, stream>>>(bsum);
    scan_add_kernel<<<NBLK_SCAN, 256, 0, stream>>>(offs_tmp, bsum, offs, cnt);
    scatter_kernel<<<NBLK_HIST, 256, 0, stream>>>(row, col, cnt, esrc);

    gemm_qkv_reg<<<dim3(NBLK_G64, 3), 256, 0, stream>>>(tb2, xb2, Wb2, bq, bk, bv, Qb, KVb, N_NODES);

    node_fused_kernel<<<(N_NODES * 64 + 255) / 256, 256, 0, stream>>>(
        Qb, KVb, rel, offs, esrc, outagg2);

    gemm_o_reg<<<NBLK_G64, 256, 0, stream>>>(outagg2, Wb2, bo, (float*)d_out, N_NODES);
}

// Round 12
// 251.967 us; speedup vs baseline: 1.1100x; 1.1100x over previous
//
#include <hip/hip_runtime.h>
#include <hip/hip_bf16.h>

#define N_NODES   50000
#define N_USERS   20000
#define N_EDGES   800000
#define DIM       256
#define NHEAD     8
#define DKH       32
#define NBLK_SCAN ((N_NODES + 255) / 256)   // 196
#define NGRP      (N_NODES / 16)            // 3125
#define NGRP_PAD  3128
#define SLOTS_NODE (NGRP * 8 * 64)          // 1.6M fragment slots per node matrix
#define NBLK_CAST (SLOTS_NODE / 256)        // 6250
#define NBLK_HIST ((N_EDGES + 255) / 256)   // 3125
#define NBLK_G64  (NGRP_PAD / 4)            // 782 row-tiles of 64
#define KVROW     768                       // 256B K-fp8 + 512B V-bf16

typedef __attribute__((ext_vector_type(8))) short bf16x8;
typedef __attribute__((ext_vector_type(4))) float f32x4;
typedef __attribute__((ext_vector_type(4))) unsigned short u16x4;
typedef __attribute__((ext_vector_type(8))) unsigned short u16x8;

__device__ inline unsigned short f2bf(float f) {
    union { __hip_bfloat16 b; unsigned short u; } cv;
    cv.b = __float2bfloat16(f);
    return cv.u;
}
__device__ inline float bf2f(unsigned short u) {
    return __uint_as_float(((unsigned int)u) << 16);
}
__device__ inline unsigned char f2fp8(float f) {
    unsigned int p = __builtin_amdgcn_cvt_pk_fp8_f32(f, f, 0, false);
    return (unsigned char)(p & 0xff);
}

// Fragment-tiled layout: elem (r, d) -> ((r>>4)*8 + (d>>5))*512 + ((d>>3)&3)*128 + (r&15)*8 + (d&7)

// ---------------- prep: weight cast | input cast | degree histogram + edge rank ----------------
__global__ void prep_kernel(const float* __restrict__ Wq, const float* __restrict__ Wk,
                            const float* __restrict__ Wv, const float* __restrict__ Wo,
                            unsigned short* __restrict__ Wb2,
                            const float* __restrict__ x,
                            const float* __restrict__ user, const float* __restrict__ item,
                            unsigned short* __restrict__ xb2, unsigned short* __restrict__ tb2,
                            const int* __restrict__ col, int* __restrict__ cnt,
                            int* __restrict__ erank)
{
    int b = blockIdx.x;
    if (b < 128) {
        int gid = b * 256 + threadIdx.x;
        const float* srcs[4] = { Wq, Wk, Wv, Wo };
        int m = gid >> 13, slot = gid & 8191;
        int lane = slot & 63, ks = (slot >> 6) & 7, g = slot >> 9;
        int c = g * 16 + (lane & 15);
        int d = ks * 32 + (lane >> 4) * 8;
        const float* s = srcs[m] + (size_t)c * DIM + d;
        float4 f0 = *(const float4*)s, f1 = *(const float4*)(s + 4);
        u16x8 o = { f2bf(f0.x), f2bf(f0.y), f2bf(f0.z), f2bf(f0.w),
                    f2bf(f1.x), f2bf(f1.y), f2bf(f1.z), f2bf(f1.w) };
        *(u16x8*)(Wb2 + (size_t)m * 65536 + (size_t)slot * 8) = o;
    } else if (b < 128 + NBLK_CAST) {
        int slot = (b - 128) * 256 + threadIdx.x;
        int lane = slot & 63, ks = (slot >> 6) & 7, g = slot >> 9;
        int r = g * 16 + (lane & 15);
        int d = ks * 32 + (lane >> 4) * 8;

        const float* sx = x + (size_t)r * DIM + d;
        float4 f0 = *(const float4*)sx, f1 = *(const float4*)(sx + 4);
        u16x8 xo = { f2bf(f0.x), f2bf(f0.y), f2bf(f0.z), f2bf(f0.w),
                     f2bf(f1.x), f2bf(f1.y), f2bf(f1.z), f2bf(f1.w) };
        *(u16x8*)(xb2 + (size_t)slot * 8) = xo;

        const float* st = (r < N_USERS) ? user + (size_t)r * DIM + d
                                        : item + (size_t)(r - N_USERS) * DIM + d;
        float4 t0 = *(const float4*)st, t1 = *(const float4*)(st + 4);
        u16x8 to = { f2bf(t0.x), f2bf(t0.y), f2bf(t0.z), f2bf(t0.w),
                     f2bf(t1.x), f2bf(t1.y), f2bf(t1.z), f2bf(t1.w) };
        *(u16x8*)(tb2 + (size_t)slot * 8) = to;
    } else {
        int e = (b - 128 - NBLK_CAST) * 256 + threadIdx.x;
        if (e < N_EDGES) erank[e] = atomicAdd(&cnt[col[e]], 1);
    }
}

// ---------------- 64-row x 256-col register-direct MFMA GEMM core ----------------
__device__ __forceinline__ void mfma_core64(const unsigned short* __restrict__ A2,
                                            const unsigned short* __restrict__ W2,
                                            int row0, f32x4 acc[2][8],
                                            int lane, int wid)
{
    const int gA = (row0 >> 4) + (wid >> 1) * 2;
    const int gB = (wid & 1) * 8;
    #pragma unroll
    for (int ks = 0; ks < 8; ++ks) {
        bf16x8 a[2], b[8];
        #pragma unroll
        for (int i = 0; i < 2; ++i)
            a[i] = *(const bf16x8*)(A2 + (size_t)((gA + i) * 8 + ks) * 512 + lane * 8);
        #pragma unroll
        for (int j = 0; j < 8; ++j)
            b[j] = *(const bf16x8*)(W2 + (size_t)((gB + j) * 8 + ks) * 512 + lane * 8);
        #pragma unroll
        for (int i = 0; i < 2; ++i)
            #pragma unroll
            for (int j = 0; j < 8; ++j)
                acc[i][j] = __builtin_amdgcn_mfma_f32_16x16x32_bf16(a[i], b[j], acc[i][j], 0, 0, 0);
    }
}

// Epilogue MODE: 0 = fp32 linear, 1 = bf16 linear, 2 = KV K-half (fp8), 3 = KV V-half (bf16)
template<int MODE>
__device__ __forceinline__ void epilogue64(f32x4 acc[2][8], const float* bias, void* Cv,
                                           int row0, int M, int lane, int wid)
{
    const int wm = wid >> 1, wn = wid & 1;
    const int lr = lane & 15, lk = lane >> 4;
    float* Cf = (float*)Cv;
    unsigned short* Cb = (unsigned short*)Cv;
    unsigned char* C8 = (unsigned char*)Cv;
    #pragma unroll
    for (int i = 0; i < 2; ++i) {
        #pragma unroll
        for (int r = 0; r < 4; ++r) {
            int grow = row0 + wm * 32 + i * 16 + lk * 4 + r;
            if (grow >= M) continue;
            #pragma unroll
            for (int j = 0; j < 8; ++j) {
                int gcol = wn * 128 + j * 16 + lr;
                float val = acc[i][j][r] + bias[gcol];
                if constexpr (MODE == 0) {
                    Cf[(size_t)grow * 256 + gcol] = val;
                } else if constexpr (MODE == 1) {
                    Cb[(size_t)grow * 256 + gcol] = f2bf(val);
                } else if constexpr (MODE == 2) {
                    C8[(size_t)grow * KVROW + gcol] = f2fp8(val);
                } else {
                    *(unsigned short*)(C8 + (size_t)grow * KVROW + 256 + gcol * 2) = f2bf(val);
                }
            }
        }
    }
}

// Fused scatter + Q/K/V GEMM. 1D grid: [0, NBLK_HIST) = scatter (atomic-free, rank-based);
// rest = GEMM, mat = gb / NBLK_G64, row-tile = gb % NBLK_G64.
__global__ __launch_bounds__(256) void gemm_qkv_scatter(
    const unsigned short* __restrict__ tb2, const unsigned short* __restrict__ xb2,
    const unsigned short* __restrict__ Wb2,
    const float* __restrict__ bq, const float* __restrict__ bk, const float* __restrict__ bv,
    unsigned short* __restrict__ Qb, unsigned char* __restrict__ KVb, int M,
    const int* __restrict__ row, const int* __restrict__ col,
    const int* __restrict__ erank, const int* __restrict__ offs,
    int* __restrict__ esrc)
{
    const int b = blockIdx.x;
    if (b < NBLK_HIST) {
        int e = b * 256 + threadIdx.x;
        if (e < N_EDGES) {
            int c = col[e];
            esrc[offs[c] + erank[e]] = row[e];
        }
        return;
    }
    const int gb = b - NBLK_HIST;
    const int mat = gb / NBLK_G64;
    const int row0 = (gb % NBLK_G64) * 64;
    const int tid = threadIdx.x;
    const int lane = tid & 63, wid = tid >> 6;

    const unsigned short* A2 = (mat == 2) ? xb2 : tb2;
    const unsigned short* W2 = Wb2 + (size_t)mat * 65536;

    f32x4 acc[2][8];
    #pragma unroll
    for (int i = 0; i < 2; ++i)
        #pragma unroll
        for (int j = 0; j < 8; ++j) acc[i][j] = (f32x4){0.f, 0.f, 0.f, 0.f};

    mfma_core64(A2, W2, row0, acc, lane, wid);

    if (mat == 0)      epilogue64<1>(acc, bq, Qb,  row0, M, lane, wid);
    else if (mat == 1) epilogue64<2>(acc, bk, KVb, row0, M, lane, wid);
    else               epilogue64<3>(acc, bv, KVb, row0, M, lane, wid);
}

// Final O GEMM: fragment-tiled bf16 A (from node kernel), fp32 out
__global__ __launch_bounds__(256) void gemm_o_reg(
    const unsigned short* __restrict__ A2,
    const unsigned short* __restrict__ Wb2, const float* __restrict__ bo,
    float* __restrict__ C, int M)
{
    const int tid = threadIdx.x;
    const int lane = tid & 63, wid = tid >> 6;
    const int row0 = blockIdx.x * 64;

    f32x4 acc[2][8];
    #pragma unroll
    for (int i = 0; i < 2; ++i)
        #pragma unroll
        for (int j = 0; j < 8; ++j) acc[i][j] = (f32x4){0.f, 0.f, 0.f, 0.f};

    mfma_core64(A2, Wb2 + 3 * 65536, row0, acc, lane, wid);
    epilogue64<0>(acc, bo, C, row0, M, lane, wid);
}

// ---------------- CSR scans ----------------
__global__ __launch_bounds__(256) void scan_blk_kernel(const int* __restrict__ cnt,
                                                       int* __restrict__ offs_tmp,
                                                       int* __restrict__ bsum) {
    __shared__ int s[256];
    int b = blockIdx.x, t = threadIdx.x;
    int i = b * 256 + t;
    int v = (i < N_NODES) ? cnt[i] : 0;
    s[t] = v;
    __syncthreads();
    #pragma unroll
    for (int d = 1; d < 256; d <<= 1) {
        int u = (t >= d) ? s[t - d] : 0;
        __syncthreads();
        s[t] += u;
        __syncthreads();
    }
    if (i < N_NODES) offs_tmp[i] = s[t] - v;
    if (t == 255) bsum[b] = s[255];
}

__global__ __launch_bounds__(256) void scan_top_kernel(int* __restrict__ bsum) {
    __shared__ int s[256];
    int t = threadIdx.x;
    int v = (t < NBLK_SCAN) ? bsum[t] : 0;
    s[t] = v;
    __syncthreads();
    #pragma unroll
    for (int d = 1; d < 256; d <<= 1) {
        int u = (t >= d) ? s[t - d] : 0;
        __syncthreads();
        s[t] += u;
        __syncthreads();
    }
    if (t < NBLK_SCAN) bsum[t] = s[t] - v;
}

__global__ __launch_bounds__(256) void scan_add_kernel(const int* __restrict__ offs_tmp,
                                                       const int* __restrict__ bsum,
                                                       int* __restrict__ offs) {
    int i = blockIdx.x * 256 + threadIdx.x;
    if (i == 0) offs[N_NODES] = N_EDGES;
    if (i >= N_NODES) return;
    offs[i] = offs_tmp[i] + bsum[blockIdx.x];
}

// ---------------- fused edge phase: one wave per destination node ----------------
// K fp8 (4B/lane) + V bf16 (8B/lane): 768B/edge row. 8-deep gather pipeline.
__global__ __launch_bounds__(256) void node_fused_kernel(
    const unsigned short* __restrict__ Qb, const unsigned char* __restrict__ KVb,
    const float* __restrict__ rel,
    const int* __restrict__ offs, const int* __restrict__ esrc,
    unsigned short* __restrict__ outagg2)
{
    const float SC = 0.17677669529663687f;  // 1/sqrt(32)
    int wid = (blockIdx.x * blockDim.x + threadIdx.x) >> 6;
    int lane = threadIdx.x & 63;
    if (wid >= N_NODES) return;
    int beg = offs[wid], end = offs[wid + 1];
    int d0 = lane * 4;
    const unsigned char* kbase = KVb + lane * 4;
    const unsigned char* vbase = KVb + 256 + lane * 8;

    u16x4 qb4 = *(const u16x4*)(Qb + (size_t)wid * DIM + d0);
    float qx = bf2f(qb4[0]), qy = bf2f(qb4[1]), qz = bf2f(qb4[2]), qw = bf2f(qb4[3]);
    float4 rl = *(const float4*)(rel + d0);

    float p0 = qx * rl.x + qy * rl.y + qz * rl.z + qw * rl.w;
    p0 += __shfl_xor(p0, 1);
    p0 += __shfl_xor(p0, 2);
    p0 += __shfl_xor(p0, 4);

    float den = 0.f;
    float4 acc = make_float4(0.f, 0.f, 0.f, 0.f);

    for (int base = beg; base < end; base += 64) {
        int n = end - base; if (n > 64) n = 64;
        int idx = base + lane; if (idx >= end) idx = end - 1;
        int my = esrc[idx];
        int j = 0;
        for (; j + 8 <= n; j += 8) {
            unsigned int kw[8]; u16x4 vv[8];
            #pragma unroll
            for (int u = 0; u < 8; ++u) {
                int r = __shfl(my, j + u);
                size_t ro = (size_t)r * KVROW;
                kw[u] = *(const unsigned int*)(kbase + ro);
                vv[u] = *(const u16x4*)(vbase + ro);
            }
            float s[8];
            #pragma unroll
            for (int u = 0; u < 8; ++u)
                s[u] = qx * __builtin_amdgcn_cvt_f32_fp8(kw[u], 0)
                     + qy * __builtin_amdgcn_cvt_f32_fp8(kw[u], 1)
                     + qz * __builtin_amdgcn_cvt_f32_fp8(kw[u], 2)
                     + qw * __builtin_amdgcn_cvt_f32_fp8(kw[u], 3);
            #pragma unroll
            for (int u = 0; u < 8; ++u) {
                s[u] += __shfl_xor(s[u], 1);
                s[u] += __shfl_xor(s[u], 2);
                s[u] += __shfl_xor(s[u], 4);
            }
            #pragma unroll
            for (int u = 0; u < 8; ++u) {
                float w = __expf((s[u] + p0) * SC);
                den += w;
                acc.x += w * bf2f(vv[u][0]); acc.y += w * bf2f(vv[u][1]);
                acc.z += w * bf2f(vv[u][2]); acc.w += w * bf2f(vv[u][3]);
            }
        }
        for (; j + 4 <= n; j += 4) {
            unsigned int kw[4]; u16x4 vv[4];
            #pragma unroll
            for (int u = 0; u < 4; ++u) {
                int r = __shfl(my, j + u);
                size_t ro = (size_t)r * KVROW;
                kw[u] = *(const unsigned int*)(kbase + ro);
                vv[u] = *(const u16x4*)(vbase + ro);
            }
            float s[4];
            #pragma unroll
            for (int u = 0; u < 4; ++u)
                s[u] = qx * __builtin_amdgcn_cvt_f32_fp8(kw[u], 0)
                     + qy * __builtin_amdgcn_cvt_f32_fp8(kw[u], 1)
                     + qz * __builtin_amdgcn_cvt_f32_fp8(kw[u], 2)
                     + qw * __builtin_amdgcn_cvt_f32_fp8(kw[u], 3);
            #pragma unroll
            for (int u = 0; u < 4; ++u) {
                s[u] += __shfl_xor(s[u], 1);
                s[u] += __shfl_xor(s[u], 2);
                s[u] += __shfl_xor(s[u], 4);
            }
            #pragma unroll
            for (int u = 0; u < 4; ++u) {
                float w = __expf((s[u] + p0) * SC);
                den += w;
                acc.x += w * bf2f(vv[u][0]); acc.y += w * bf2f(vv[u][1]);
                acc.z += w * bf2f(vv[u][2]); acc.w += w * bf2f(vv[u][3]);
            }
        }
        for (; j < n; ++j) {
            int r = __shfl(my, j);
            size_t ro = (size_t)r * KVROW;
            unsigned int kw = *(const unsigned int*)(kbase + ro);
            u16x4 vv = *(const u16x4*)(vbase + ro);
            float s0 = qx * __builtin_amdgcn_cvt_f32_fp8(kw, 0)
                     + qy * __builtin_amdgcn_cvt_f32_fp8(kw, 1)
                     + qz * __builtin_amdgcn_cvt_f32_fp8(kw, 2)
                     + qw * __builtin_amdgcn_cvt_f32_fp8(kw, 3);
            s0 += __shfl_xor(s0, 1);
            s0 += __shfl_xor(s0, 2);
            s0 += __shfl_xor(s0, 4);
            float w0 = __expf((s0 + p0) * SC);
            den += w0;
            acc.x += w0 * bf2f(vv[0]); acc.y += w0 * bf2f(vv[1]);
            acc.z += w0 * bf2f(vv[2]); acc.w += w0 * bf2f(vv[3]);
        }
    }
    float rden = (end > beg) ? 1.f / den : 0.f;
    u16x4 o = { f2bf(acc.x * rden), f2bf(acc.y * rden),
                f2bf(acc.z * rden), f2bf(acc.w * rden) };
    int ks = lane >> 3, lk = (lane >> 1) & 3, e4 = (lane & 1) * 4;
    size_t toff = ((size_t)(wid >> 4) * 8 + ks) * 512 + (lk * 16 + (wid & 15)) * 8 + e4;
    *(u16x4*)(outagg2 + toff) = o;
}

extern "C" void kernel_launch(void* const* d_in, const int* in_sizes, int n_in,
                              void* d_out, int out_size, void* d_ws, size_t ws_size,
                              hipStream_t stream) {
    const float* x    = (const float*)d_in[0];
    const int*   row  = (const int*)d_in[1];
    const int*   col  = (const int*)d_in[2];
    const float* rel  = (const float*)d_in[3];
    const float* user = (const float*)d_in[4];
    const float* item = (const float*)d_in[5];
    const float* Wq   = (const float*)d_in[6];
    const float* bq   = (const float*)d_in[7];
    const float* Wk   = (const float*)d_in[8];
    const float* bk   = (const float*)d_in[9];
    const float* Wv   = (const float*)d_in[10];
    const float* bv   = (const float*)d_in[11];
    const float* Wo   = (const float*)d_in[12];
    const float* bo   = (const float*)d_in[13];

    char* ws = (char*)d_ws;
    size_t off = 0;
    auto alloc = [&](size_t bytes) -> void* {
        void* p = ws + off;
        off = (off + bytes + 255) & ~(size_t)255;
        return p;
    };
    const size_t tiled_sz = (size_t)NGRP_PAD * 4096 * 2;
    unsigned short* Qb      = (unsigned short*)alloc((size_t)N_NODES * DIM * 2);
    unsigned char*  KVb     = (unsigned char*)alloc((size_t)N_NODES * KVROW);
    unsigned short* xb2     = (unsigned short*)alloc(tiled_sz);
    unsigned short* tb2     = (unsigned short*)alloc(tiled_sz);
    unsigned short* outagg2 = (unsigned short*)alloc(tiled_sz);
    unsigned short* Wb2     = (unsigned short*)alloc((size_t)4 * 65536 * 2);
    int*   cnt      = (int*)alloc((size_t)N_NODES * 4);
    int*   offs     = (int*)alloc((size_t)(N_NODES + 1) * 4);
    int*   offs_tmp = (int*)alloc((size_t)N_NODES * 4);
    int*   bsum     = (int*)alloc((size_t)NBLK_SCAN * 4);
    int*   esrc     = (int*)alloc((size_t)N_EDGES * 4);
    int*   erank    = (int*)alloc((size_t)N_EDGES * 4);

    hipMemsetAsync(cnt, 0, (size_t)N_NODES * 4, stream);

    prep_kernel<<<128 + NBLK_CAST + NBLK_HIST, 256, 0, stream>>>(
        Wq, Wk, Wv, Wo, Wb2, x, user, item, xb2, tb2, col, cnt, erank);
    scan_blk_kernel<<<NBLK_SCAN, 256, 0, stream>>>(cnt, offs_tmp, bsum);
    scan_top_kernel<<<1, 256, 0, stream>>>(bsum);
    scan_add_kernel<<<NBLK_SCAN, 256, 0, stream>>>(offs_tmp, bsum, offs);

    gemm_qkv_scatter<<<NBLK_HIST + 3 * NBLK_G64, 256, 0, stream>>>(
        tb2, xb2, Wb2, bq, bk, bv, Qb, KVb, N_NODES,
        row, col, erank, offs, esrc);

    node_fused_kernel<<<(N_NODES * 64 + 255) / 256, 256, 0, stream>>>(
        Qb, KVb, rel, offs, esrc, outagg2);

    gemm_o_reg<<<NBLK_G64, 256, 0, stream>>>(outagg2, Wb2, bo, (float*)d_out, N_NODES);
}

// Round 13
// 226.554 us; speedup vs baseline: 1.2345x; 1.1122x over previous
//
#include <hip/hip_runtime.h>
#include <hip/hip_bf16.h>

#define N_NODES   50000
#define N_USERS   20000
#define N_EDGES   800000
#define DIM       256
#define NHEAD     8
#define DKH       32
#define NBLK_SCAN ((N_NODES + 255) / 256)   // 196
#define NGRP_PAD  3128
#define NBLK_HIST ((N_EDGES + 255) / 256)   // 3125
#define NBLK_G64  (NGRP_PAD / 4)            // 782 row-tiles of 64
#define KVROW     768                       // 256B K-fp8 + 512B V-bf16

typedef __attribute__((ext_vector_type(8))) short bf16x8;
typedef __attribute__((ext_vector_type(4))) float f32x4;
typedef __attribute__((ext_vector_type(4))) unsigned short u16x4;
typedef __attribute__((ext_vector_type(8))) unsigned short u16x8;

__device__ inline unsigned short f2bf(float f) {
    union { __hip_bfloat16 b; unsigned short u; } cv;
    cv.b = __float2bfloat16(f);
    return cv.u;
}
__device__ inline float bf2f(unsigned short u) {
    return __uint_as_float(((unsigned int)u) << 16);
}
__device__ inline unsigned char f2fp8(float f) {
    unsigned int p = __builtin_amdgcn_cvt_pk_fp8_f32(f, f, 0, false);
    return (unsigned char)(p & 0xff);
}

// Fragment-tiled layout (bytes): elem (r,d) -> ((r>>4)*8 + (d>>5))*1024 + ((d>>3)&3)*256 + (r&15)*16 + (d&7)*2
// One MFMA fragment = 64 lanes x 16 B contiguous = 1KB.

// ---------------- prep: weight cast | degree histogram + edge rank ----------------
__global__ void prep_kernel(const float* __restrict__ Wq, const float* __restrict__ Wk,
                            const float* __restrict__ Wv, const float* __restrict__ Wo,
                            unsigned short* __restrict__ Wb2,
                            const int* __restrict__ col, int* __restrict__ cnt,
                            int* __restrict__ erank)
{
    int b = blockIdx.x;
    if (b < 128) {
        int gid = b * 256 + threadIdx.x;
        const float* srcs[4] = { Wq, Wk, Wv, Wo };
        int m = gid >> 13, slot = gid & 8191;
        int lane = slot & 63, ks = (slot >> 6) & 7, g = slot >> 9;
        int c = g * 16 + (lane & 15);
        int d = ks * 32 + (lane >> 4) * 8;
        const float* s = srcs[m] + (size_t)c * DIM + d;
        float4 f0 = *(const float4*)s, f1 = *(const float4*)(s + 4);
        u16x8 o = { f2bf(f0.x), f2bf(f0.y), f2bf(f0.z), f2bf(f0.w),
                    f2bf(f1.x), f2bf(f1.y), f2bf(f1.z), f2bf(f1.w) };
        *(u16x8*)(Wb2 + (size_t)m * 65536 + (size_t)slot * 8) = o;
    } else {
        int e = (b - 128) * 256 + threadIdx.x;
        if (e < N_EDGES) erank[e] = atomicAdd(&cnt[col[e]], 1);
    }
}

// ---------------- stage 64x256 fp32 tile -> fragment-tiled bf16 in LDS ----------------
// Coalesced reads (32 threads cover 1KB of a row), 8 iters of 8 rows.
__device__ __forceinline__ void stage_a_lds(const float* __restrict__ Alo,
                                            const float* __restrict__ Ahi,
                                            int split, int row0, int M,
                                            unsigned short* Asm, int tid)
{
    const int d0 = (tid & 31) * 8;
    const int rb = tid >> 5;
    #pragma unroll
    for (int it = 0; it < 8; ++it) {
        int r = it * 8 + rb;
        int ga = row0 + r; if (ga >= M) ga = M - 1;
        const float* src = ((ga < split) ? Alo + (size_t)ga * DIM
                                         : Ahi + (size_t)(ga - split) * DIM) + d0;
        float4 f0 = *(const float4*)src, f1 = *(const float4*)(src + 4);
        u16x8 hv = { f2bf(f0.x), f2bf(f0.y), f2bf(f0.z), f2bf(f0.w),
                     f2bf(f1.x), f2bf(f1.y), f2bf(f1.z), f2bf(f1.w) };
        int g = r >> 4, ks = d0 >> 5, sub = (d0 >> 3) & 3;
        *(u16x8*)((char*)Asm + (size_t)(g * 8 + ks) * 1024 + sub * 256 + (r & 15) * 16) = hv;
    }
}

// ---------------- 64x256 MFMA core: A from LDS, W register-direct ----------------
__device__ __forceinline__ void mfma_core_lds(const unsigned short* Asm,
                                              const unsigned short* __restrict__ W2,
                                              f32x4 acc[2][8], int lane, int wid)
{
    const int gAl = (wid >> 1) * 2;
    const int gB = (wid & 1) * 8;
    #pragma unroll
    for (int ks = 0; ks < 8; ++ks) {
        bf16x8 a[2], b[8];
        #pragma unroll
        for (int i = 0; i < 2; ++i)
            a[i] = *(const bf16x8*)((const char*)Asm + (size_t)((gAl + i) * 8 + ks) * 1024 + lane * 16);
        #pragma unroll
        for (int j = 0; j < 8; ++j)
            b[j] = *(const bf16x8*)(W2 + (size_t)((gB + j) * 8 + ks) * 512 + lane * 8);
        #pragma unroll
        for (int i = 0; i < 2; ++i)
            #pragma unroll
            for (int j = 0; j < 8; ++j)
                acc[i][j] = __builtin_amdgcn_mfma_f32_16x16x32_bf16(a[i], b[j], acc[i][j], 0, 0, 0);
    }
}

// register-direct core for the O-GEMM (A pre-tiled in global from node kernel)
__device__ __forceinline__ void mfma_core64(const unsigned short* __restrict__ A2,
                                            const unsigned short* __restrict__ W2,
                                            int row0, f32x4 acc[2][8],
                                            int lane, int wid)
{
    const int gA = (row0 >> 4) + (wid >> 1) * 2;
    const int gB = (wid & 1) * 8;
    #pragma unroll
    for (int ks = 0; ks < 8; ++ks) {
        bf16x8 a[2], b[8];
        #pragma unroll
        for (int i = 0; i < 2; ++i)
            a[i] = *(const bf16x8*)(A2 + (size_t)((gA + i) * 8 + ks) * 512 + lane * 8);
        #pragma unroll
        for (int j = 0; j < 8; ++j)
            b[j] = *(const bf16x8*)(W2 + (size_t)((gB + j) * 8 + ks) * 512 + lane * 8);
        #pragma unroll
        for (int i = 0; i < 2; ++i)
            #pragma unroll
            for (int j = 0; j < 8; ++j)
                acc[i][j] = __builtin_amdgcn_mfma_f32_16x16x32_bf16(a[i], b[j], acc[i][j], 0, 0, 0);
    }
}

// Epilogue MODE: 0 = fp32 linear, 1 = bf16 linear, 2 = KV K-half (fp8), 3 = KV V-half (bf16)
template<int MODE>
__device__ __forceinline__ void epilogue64(f32x4 acc[2][8], const float* bias, void* Cv,
                                           int row0, int M, int lane, int wid)
{
    const int wm = wid >> 1, wn = wid & 1;
    const int lr = lane & 15, lk = lane >> 4;
    float* Cf = (float*)Cv;
    unsigned short* Cb = (unsigned short*)Cv;
    unsigned char* C8 = (unsigned char*)Cv;
    #pragma unroll
    for (int i = 0; i < 2; ++i) {
        #pragma unroll
        for (int r = 0; r < 4; ++r) {
            int grow = row0 + wm * 32 + i * 16 + lk * 4 + r;
            if (grow >= M) continue;
            #pragma unroll
            for (int j = 0; j < 8; ++j) {
                int gcol = wn * 128 + j * 16 + lr;
                float val = acc[i][j][r] + bias[gcol];
                if constexpr (MODE == 0) {
                    Cf[(size_t)grow * 256 + gcol] = val;
                } else if constexpr (MODE == 1) {
                    Cb[(size_t)grow * 256 + gcol] = f2bf(val);
                } else if constexpr (MODE == 2) {
                    C8[(size_t)grow * KVROW + gcol] = f2fp8(val);
                } else {
                    *(unsigned short*)(C8 + (size_t)grow * KVROW + 256 + gcol * 2) = f2bf(val);
                }
            }
        }
    }
}

// Fused scatter + QKV GEMM (LDS-staged fp32 A). 1D grid:
//   [0, NBLK_HIST): rank-based scatter (atomic-free)
//   [NBLK_HIST, +NBLK_G64): text tile -> Q AND K (A staged once)
//   [NBLK_HIST+NBLK_G64, +NBLK_G64): x tile -> V
__global__ __launch_bounds__(256) void gemm_qkv_scatter(
    const float* __restrict__ user, const float* __restrict__ item,
    const float* __restrict__ x,
    const unsigned short* __restrict__ Wb2,
    const float* __restrict__ bq, const float* __restrict__ bk, const float* __restrict__ bv,
    unsigned short* __restrict__ Qb, unsigned char* __restrict__ KVb, int M,
    const int* __restrict__ row, const int* __restrict__ col,
    const int* __restrict__ erank, const int* __restrict__ offs,
    int* __restrict__ esrc)
{
    const int b = blockIdx.x;
    if (b < NBLK_HIST) {
        int e = b * 256 + threadIdx.x;
        if (e < N_EDGES) {
            int c = col[e];
            esrc[offs[c] + erank[e]] = row[e];
        }
        return;
    }
    __shared__ unsigned short Asm[64 * 256];   // 32 KB
    const int gb = b - NBLK_HIST;
    const int isv = gb >= NBLK_G64;
    const int row0 = (isv ? gb - NBLK_G64 : gb) * 64;
    const int tid = threadIdx.x;
    const int lane = tid & 63, wid = tid >> 6;

    if (isv) stage_a_lds(x, x, M, row0, M, Asm, tid);
    else     stage_a_lds(user, item, N_USERS, row0, M, Asm, tid);
    __syncthreads();

    f32x4 acc[2][8];
    if (isv) {
        #pragma unroll
        for (int i = 0; i < 2; ++i)
            #pragma unroll
            for (int j = 0; j < 8; ++j) acc[i][j] = (f32x4){0.f, 0.f, 0.f, 0.f};
        mfma_core_lds(Asm, Wb2 + 2 * 65536, acc, lane, wid);
        epilogue64<3>(acc, bv, KVb, row0, M, lane, wid);
    } else {
        // Q
        #pragma unroll
        for (int i = 0; i < 2; ++i)
            #pragma unroll
            for (int j = 0; j < 8; ++j) acc[i][j] = (f32x4){0.f, 0.f, 0.f, 0.f};
        mfma_core_lds(Asm, Wb2, acc, lane, wid);
        epilogue64<1>(acc, bq, Qb, row0, M, lane, wid);
        // K (same staged A)
        #pragma unroll
        for (int i = 0; i < 2; ++i)
            #pragma unroll
            for (int j = 0; j < 8; ++j) acc[i][j] = (f32x4){0.f, 0.f, 0.f, 0.f};
        mfma_core_lds(Asm, Wb2 + 65536, acc, lane, wid);
        epilogue64<2>(acc, bk, KVb, row0, M, lane, wid);
    }
}

// Final O GEMM: fragment-tiled bf16 A (from node kernel), fp32 out
__global__ __launch_bounds__(256) void gemm_o_reg(
    const unsigned short* __restrict__ A2,
    const unsigned short* __restrict__ Wb2, const float* __restrict__ bo,
    float* __restrict__ C, int M)
{
    const int tid = threadIdx.x;
    const int lane = tid & 63, wid = tid >> 6;
    const int row0 = blockIdx.x * 64;

    f32x4 acc[2][8];
    #pragma unroll
    for (int i = 0; i < 2; ++i)
        #pragma unroll
        for (int j = 0; j < 8; ++j) acc[i][j] = (f32x4){0.f, 0.f, 0.f, 0.f};

    mfma_core64(A2, Wb2 + 3 * 65536, row0, acc, lane, wid);
    epilogue64<0>(acc, bo, C, row0, M, lane, wid);
}

// ---------------- CSR scans ----------------
__global__ __launch_bounds__(256) void scan_blk_kernel(const int* __restrict__ cnt,
                                                       int* __restrict__ offs_tmp,
                                                       int* __restrict__ bsum) {
    __shared__ int s[256];
    int b = blockIdx.x, t = threadIdx.x;
    int i = b * 256 + t;
    int v = (i < N_NODES) ? cnt[i] : 0;
    s[t] = v;
    __syncthreads();
    #pragma unroll
    for (int d = 1; d < 256; d <<= 1) {
        int u = (t >= d) ? s[t - d] : 0;
        __syncthreads();
        s[t] += u;
        __syncthreads();
    }
    if (i < N_NODES) offs_tmp[i] = s[t] - v;
    if (t == 255) bsum[b] = s[255];
}

__global__ __launch_bounds__(256) void scan_top_kernel(int* __restrict__ bsum) {
    __shared__ int s[256];
    int t = threadIdx.x;
    int v = (t < NBLK_SCAN) ? bsum[t] : 0;
    s[t] = v;
    __syncthreads();
    #pragma unroll
    for (int d = 1; d < 256; d <<= 1) {
        int u = (t >= d) ? s[t - d] : 0;
        __syncthreads();
        s[t] += u;
        __syncthreads();
    }
    if (t < NBLK_SCAN) bsum[t] = s[t] - v;
}

__global__ __launch_bounds__(256) void scan_add_kernel(const int* __restrict__ offs_tmp,
                                                       const int* __restrict__ bsum,
                                                       int* __restrict__ offs) {
    int i = blockIdx.x * 256 + threadIdx.x;
    if (i == 0) offs[N_NODES] = N_EDGES;
    if (i >= N_NODES) return;
    offs[i] = offs_tmp[i] + bsum[blockIdx.x];
}

// ---------------- fused edge phase: one wave per destination node ----------------
// K fp8 (4B/lane) + V bf16 (8B/lane): 768B/edge row. 8-deep gather pipeline.
__global__ __launch_bounds__(256) void node_fused_kernel(
    const unsigned short* __restrict__ Qb, const unsigned char* __restrict__ KVb,
    const float* __restrict__ rel,
    const int* __restrict__ offs, const int* __restrict__ esrc,
    unsigned short* __restrict__ outagg2)
{
    const float SC = 0.17677669529663687f;  // 1/sqrt(32)
    int wid = (blockIdx.x * blockDim.x + threadIdx.x) >> 6;
    int lane = threadIdx.x & 63;
    if (wid >= N_NODES) return;
    int beg = offs[wid], end = offs[wid + 1];
    int d0 = lane * 4;
    const unsigned char* kbase = KVb + lane * 4;
    const unsigned char* vbase = KVb + 256 + lane * 8;

    u16x4 qb4 = *(const u16x4*)(Qb + (size_t)wid * DIM + d0);
    float qx = bf2f(qb4[0]), qy = bf2f(qb4[1]), qz = bf2f(qb4[2]), qw = bf2f(qb4[3]);
    float4 rl = *(const float4*)(rel + d0);

    float p0 = qx * rl.x + qy * rl.y + qz * rl.z + qw * rl.w;
    p0 += __shfl_xor(p0, 1);
    p0 += __shfl_xor(p0, 2);
    p0 += __shfl_xor(p0, 4);

    float den = 0.f;
    float4 acc = make_float4(0.f, 0.f, 0.f, 0.f);

    for (int base = beg; base < end; base += 64) {
        int n = end - base; if (n > 64) n = 64;
        int idx = base + lane; if (idx >= end) idx = end - 1;
        int my = esrc[idx];
        int j = 0;
        for (; j + 8 <= n; j += 8) {
            unsigned int kw[8]; u16x4 vv[8];
            #pragma unroll
            for (int u = 0; u < 8; ++u) {
                int r = __shfl(my, j + u);
                size_t ro = (size_t)r * KVROW;
                kw[u] = *(const unsigned int*)(kbase + ro);
                vv[u] = *(const u16x4*)(vbase + ro);
            }
            float s[8];
            #pragma unroll
            for (int u = 0; u < 8; ++u)
                s[u] = qx * __builtin_amdgcn_cvt_f32_fp8(kw[u], 0)
                     + qy * __builtin_amdgcn_cvt_f32_fp8(kw[u], 1)
                     + qz * __builtin_amdgcn_cvt_f32_fp8(kw[u], 2)
                     + qw * __builtin_amdgcn_cvt_f32_fp8(kw[u], 3);
            #pragma unroll
            for (int u = 0; u < 8; ++u) {
                s[u] += __shfl_xor(s[u], 1);
                s[u] += __shfl_xor(s[u], 2);
                s[u] += __shfl_xor(s[u], 4);
            }
            #pragma unroll
            for (int u = 0; u < 8; ++u) {
                float w = __expf((s[u] + p0) * SC);
                den += w;
                acc.x += w * bf2f(vv[u][0]); acc.y += w * bf2f(vv[u][1]);
                acc.z += w * bf2f(vv[u][2]); acc.w += w * bf2f(vv[u][3]);
            }
        }
        for (; j + 4 <= n; j += 4) {
            unsigned int kw[4]; u16x4 vv[4];
            #pragma unroll
            for (int u = 0; u < 4; ++u) {
                int r = __shfl(my, j + u);
                size_t ro = (size_t)r * KVROW;
                kw[u] = *(const unsigned int*)(kbase + ro);
                vv[u] = *(const u16x4*)(vbase + ro);
            }
            float s[4];
            #pragma unroll
            for (int u = 0; u < 4; ++u)
                s[u] = qx * __builtin_amdgcn_cvt_f32_fp8(kw[u], 0)
                     + qy * __builtin_amdgcn_cvt_f32_fp8(kw[u], 1)
                     + qz * __builtin_amdgcn_cvt_f32_fp8(kw[u], 2)
                     + qw * __builtin_amdgcn_cvt_f32_fp8(kw[u], 3);
            #pragma unroll
            for (int u = 0; u < 4; ++u) {
                s[u] += __shfl_xor(s[u], 1);
                s[u] += __shfl_xor(s[u], 2);
                s[u] += __shfl_xor(s[u], 4);
            }
            #pragma unroll
            for (int u = 0; u < 4; ++u) {
                float w = __expf((s[u] + p0) * SC);
                den += w;
                acc.x += w * bf2f(vv[u][0]); acc.y += w * bf2f(vv[u][1]);
                acc.z += w * bf2f(vv[u][2]); acc.w += w * bf2f(vv[u][3]);
            }
        }
        for (; j < n; ++j) {
            int r = __shfl(my, j);
            size_t ro = (size_t)r * KVROW;
            unsigned int kw = *(const unsigned int*)(kbase + ro);
            u16x4 vv = *(const u16x4*)(vbase + ro);
            float s0 = qx * __builtin_amdgcn_cvt_f32_fp8(kw, 0)
                     + qy * __builtin_amdgcn_cvt_f32_fp8(kw, 1)
                     + qz * __builtin_amdgcn_cvt_f32_fp8(kw, 2)
                     + qw * __builtin_amdgcn_cvt_f32_fp8(kw, 3);
            s0 += __shfl_xor(s0, 1);
            s0 += __shfl_xor(s0, 2);
            s0 += __shfl_xor(s0, 4);
            float w0 = __expf((s0 + p0) * SC);
            den += w0;
            acc.x += w0 * bf2f(vv[0]); acc.y += w0 * bf2f(vv[1]);
            acc.z += w0 * bf2f(vv[2]); acc.w += w0 * bf2f(vv[3]);
        }
    }
    float rden = (end > beg) ? 1.f / den : 0.f;
    u16x4 o = { f2bf(acc.x * rden), f2bf(acc.y * rden),
                f2bf(acc.z * rden), f2bf(acc.w * rden) };
    int ks = lane >> 3, lk = (lane >> 1) & 3, e4 = (lane & 1) * 4;
    size_t toff = ((size_t)(wid >> 4) * 8 + ks) * 512 + (lk * 16 + (wid & 15)) * 8 + e4;
    *(u16x4*)(outagg2 + toff) = o;
}

extern "C" void kernel_launch(void* const* d_in, const int* in_sizes, int n_in,
                              void* d_out, int out_size, void* d_ws, size_t ws_size,
                              hipStream_t stream) {
    const float* x    = (const float*)d_in[0];
    const int*   row  = (const int*)d_in[1];
    const int*   col  = (const int*)d_in[2];
    const float* rel  = (const float*)d_in[3];
    const float* user = (const float*)d_in[4];
    const float* item = (const float*)d_in[5];
    const float* Wq   = (const float*)d_in[6];
    const float* bq   = (const float*)d_in[7];
    const float* Wk   = (const float*)d_in[8];
    const float* bk   = (const float*)d_in[9];
    const float* Wv   = (const float*)d_in[10];
    const float* bv   = (const float*)d_in[11];
    const float* Wo   = (const float*)d_in[12];
    const float* bo   = (const float*)d_in[13];

    char* ws = (char*)d_ws;
    size_t off = 0;
    auto alloc = [&](size_t bytes) -> void* {
        void* p = ws + off;
        off = (off + bytes + 255) & ~(size_t)255;
        return p;
    };
    const size_t tiled_sz = (size_t)NGRP_PAD * 4096 * 2;
    unsigned short* Qb      = (unsigned short*)alloc((size_t)N_NODES * DIM * 2);
    unsigned char*  KVb     = (unsigned char*)alloc((size_t)N_NODES * KVROW);
    unsigned short* outagg2 = (unsigned short*)alloc(tiled_sz);
    unsigned short* Wb2     = (unsigned short*)alloc((size_t)4 * 65536 * 2);
    int*   cnt      = (int*)alloc((size_t)N_NODES * 4);
    int*   offs     = (int*)alloc((size_t)(N_NODES + 1) * 4);
    int*   offs_tmp = (int*)alloc((size_t)N_NODES * 4);
    int*   bsum     = (int*)alloc((size_t)NBLK_SCAN * 4);
    int*   esrc     = (int*)alloc((size_t)N_EDGES * 4);
    int*   erank    = (int*)alloc((size_t)N_EDGES * 4);

    hipMemsetAsync(cnt, 0, (size_t)N_NODES * 4, stream);

    prep_kernel<<<128 + NBLK_HIST, 256, 0, stream>>>(
        Wq, Wk, Wv, Wo, Wb2, col, cnt, erank);
    scan_blk_kernel<<<NBLK_SCAN, 256, 0, stream>>>(cnt, offs_tmp, bsum);
    scan_top_kernel<<<1, 256, 0, stream>>>(bsum);
    scan_add_kernel<<<NBLK_SCAN, 256, 0, stream>>>(offs_tmp, bsum, offs);

    gemm_qkv_scatter<<<NBLK_HIST + 2 * NBLK_G64, 256, 0, stream>>>(
        user, item, x, Wb2, bq, bk, bv, Qb, KVb, N_NODES,
        row, col, erank, offs, esrc);

    node_fused_kernel<<<(N_NODES * 64 + 255) / 256, 256, 0, stream>>>(
        Qb, KVb, rel, offs, esrc, outagg2);

    gemm_o_reg<<<NBLK_G64, 256, 0, stream>>>(outagg2, Wb2, bo, (float*)d_out, N_NODES);
}